// Round 7
// baseline (1096.071 us; speedup 1.0000x reference)
//
#include <hip/hip_runtime.h>
#include <hip/hip_bf16.h>

#define BB 512
#define TT 256
#define VV 128
#define EE 64
#define HH 64
#define GG 256   // 4H
#define DD 128   // 2H
#define NN1 512  // 2 dirs * 4H

typedef unsigned short ushort8_t __attribute__((ext_vector_type(8)));
typedef short s8v __attribute__((ext_vector_type(8)));
typedef float f4v __attribute__((ext_vector_type(4)));

__device__ __forceinline__ float sigf(float x){ return 1.0f/(1.0f + __expf(-x)); }
__device__ __forceinline__ float tanhfast(float x){ return 1.0f - 2.0f/(__expf(2.0f*x)+1.0f); }
__device__ __forceinline__ unsigned short f2bf(float f){
  unsigned int u = __float_as_uint(f);
  u += 0x7fffu + ((u >> 16) & 1u);
  return (unsigned short)(u >> 16);
}
__device__ __forceinline__ float bf2f(unsigned short u){
  return __uint_as_float(((unsigned int)u) << 16);
}

// ---------------- prep: embproj tables, bf16 weights, exp(trans) ----------------
__global__ void k_prep(const float* __restrict__ emb,
    const float* __restrict__ wih0f, const float* __restrict__ bih0f, const float* __restrict__ bhh0f,
    const float* __restrict__ wih0b, const float* __restrict__ bih0b, const float* __restrict__ bhh0b,
    const float* __restrict__ wih1f, const float* __restrict__ bih1f, const float* __restrict__ bhh1f,
    const float* __restrict__ wih1b, const float* __restrict__ bih1b, const float* __restrict__ bhh1b,
    const float* __restrict__ lin_w, const float* __restrict__ trans, const float* __restrict__ endv,
    const float* __restrict__ whh0f, const float* __restrict__ whh0b,
    const float* __restrict__ whh1f, const float* __restrict__ whh1b,
    float* __restrict__ P0f, float* __restrict__ P0b,
    unsigned short* __restrict__ wB1, unsigned short* __restrict__ linB,
    float* __restrict__ bias1, float* __restrict__ etrans, float* __restrict__ eend,
    unsigned short* __restrict__ whhB0f, unsigned short* __restrict__ whhB0b,
    unsigned short* __restrict__ whhB1f, unsigned short* __restrict__ whhB1b)
{
  int bid = blockIdx.x, tid = threadIdx.x;
  if (bid < 256){
    // embproj: P0[d][v][g] = emb[v,:]·wih[g,:] + b_ih[g] + b_hh[g]
    int d = bid >> 7, v = bid & 127;
    const float* wih = d ? wih0b : wih0f;
    const float* bi  = d ? bih0b : bih0f;
    const float* bh  = d ? bhh0b : bhh0f;
    float* P0 = d ? P0b : P0f;
    __shared__ __align__(16) float er[64];
    if (tid < 64) er[tid] = emb[v*64 + tid];
    __syncthreads();
    float acc = bi[tid] + bh[tid];
    const float4* w4 = (const float4*)(wih + tid*64);
    const float4* e4 = (const float4*)er;
    #pragma unroll
    for (int k=0;k<16;k++){
      float4 w = w4[k]; float4 e = e4[k];
      acc += w.x*e.x + w.y*e.y + w.z*e.z + w.w*e.w;
    }
    P0[v*GG + tid] = acc;
  } else if (bid < 320){
    // wB1[n][k] bf16, n = dir*256+g over [512], k over [128]
    int e = ((bid-256)*256 + tid)*4;
    int n = e >> 7, k = e & 127;
    const float* w = (n < 256) ? (wih1f + n*128 + k) : (wih1b + (n-256)*128 + k);
    ushort4 o; o.x=f2bf(w[0]); o.y=f2bf(w[1]); o.z=f2bf(w[2]); o.w=f2bf(w[3]);
    *(ushort4*)(wB1 + e) = o;
  } else if (bid < 336){
    // linB[v][k] bf16 (128 x 128)
    int e = ((bid-320)*256 + tid)*4;
    const float* w = lin_w + e;
    ushort4 o; o.x=f2bf(w[0]); o.y=f2bf(w[1]); o.z=f2bf(w[2]); o.w=f2bf(w[3]);
    *(ushort4*)(linB + e) = o;
  } else if (bid < 400){
    int idx = (bid-336)*256 + tid;   // 0..16383
    etrans[idx] = expf(trans[idx]);
  } else if (bid < 404){
    // whh -> bf16 tables [g][j] (256x64) for the MFMA recurrence B-frags
    int k = bid - 400;
    const float* src = (k==0)? whh0f : (k==1)? whh0b : (k==2)? whh1f : whh1b;
    unsigned short* dst = (k==0)? whhB0f : (k==1)? whhB0b : (k==2)? whhB1f : whhB1b;
    for (int i=tid; i<16384; i+=256) dst[i] = f2bf(src[i]);
  } else {
    for (int i = tid; i < 512; i += 256){
      int d = i >> 8, gg = i & 255;
      bias1[i] = d ? (bih1b[gg]+bhh1b[gg]) : (bih1f[gg]+bhh1f[gg]);
    }
    if (tid < 128) eend[tid] = expf(endv[tid]);
  }
}

// ---------------- MFMA LSTM recurrence ----------------
// R2-R6 forensic: thread-per-gate recurrence is LDS-return-BW bound (each
// thread broadcast-reads all of h: 32 ds_read_b128/thread/step ~= 2500
// cyc/step/CU; weight residency was irrelevant, which is why R3-R6 tweaks
// were all neutral). MFMA form reads h ONCE per wave via A-frags.
// Block = 16 batch rows x 1 dir, 4 waves; wave w computes g-tiles 4w..4w+3.
// whh B-frags pinned in VGPRs via volatile asm (remat-proof), bf16 tables
// prepared by k_prep. Gates go C-layout -> LDS -> thread-per-(j,b) for the
// nonlinearity; c-state stays in registers.
template<int LAYER>
__global__ __launch_bounds__(256)
__attribute__((amdgpu_waves_per_eu(1, 1)))
void k_lstm2(const int* __restrict__ x, const float* __restrict__ P0f,
             const float* __restrict__ P0b, const unsigned short* __restrict__ pre1,
             const unsigned short* __restrict__ whhBf, const unsigned short* __restrict__ whhBb,
             unsigned short* __restrict__ hout)
{
  const int bid = blockIdx.x;        // 0..63
  const int dir = bid & 1;
  const int rb  = (bid >> 1) * 16;   // batch-row base
  const int tid = threadIdx.x;
  const int w   = tid >> 6;          // wave 0..3
  const int lane= tid & 63;
  const int l16 = lane & 15, q = lane >> 4;

  __shared__ __align__(16) unsigned short hA[16*72];   // h bf16, row stride 72
  __shared__ __align__(16) float gfull[256*20];        // gates [g][b], stride 20
  __shared__ int xs[(LAYER==0) ? 16*256 : 64];

  // B-frags: whh[g][j] bf16; frag (i,ks): lane holds [g=(4w+i)*16+l16][k=ks*32+q*8..+7]
  const unsigned short* wtab = dir ? whhBb : whhBf;
  s8v bf0,bf1,bf2,bf3,bf4,bf5,bf6,bf7;
  {
    const unsigned short* p0 = wtab + ((w*4+0)*16 + l16)*64 + q*8;
    const unsigned short* p1 = wtab + ((w*4+1)*16 + l16)*64 + q*8;
    const unsigned short* p2 = wtab + ((w*4+2)*16 + l16)*64 + q*8;
    const unsigned short* p3 = wtab + ((w*4+3)*16 + l16)*64 + q*8;
    asm volatile(
      "global_load_dwordx4 %0, %8, off\n\t"
      "global_load_dwordx4 %1, %8, off offset:64\n\t"
      "global_load_dwordx4 %2, %9, off\n\t"
      "global_load_dwordx4 %3, %9, off offset:64\n\t"
      "global_load_dwordx4 %4, %10, off\n\t"
      "global_load_dwordx4 %5, %10, off offset:64\n\t"
      "global_load_dwordx4 %6, %11, off\n\t"
      "global_load_dwordx4 %7, %11, off offset:64\n\t"
      "s_waitcnt vmcnt(0)"
      : "=&v"(bf0),"=&v"(bf1),"=&v"(bf2),"=&v"(bf3),
        "=&v"(bf4),"=&v"(bf5),"=&v"(bf6),"=&v"(bf7)
      : "v"(p0),"v"(p1),"v"(p2),"v"(p3));
  }

  for (int i = tid; i < 16*72; i += 256) hA[i] = 0;
  if (LAYER==0){
    for (int i = tid; i < 16*256; i += 256) xs[i] = x[(rb + (i>>8))*TT + (i & 255)];
  }

  const float* P0 = dir ? P0b : P0f;
  const int j = tid & 63, bq = tid >> 6;   // element-phase mapping: 4 b's per thread
  float c0=0.f, c1=0.f, c2=0.f, c3=0.f;

  for (int t=0; t<TT; t++){
    const int tt = dir ? (TT-1-t) : t;
    __syncthreads();   // barrier A: hA (t-1 writes) visible; also covers init
    // ---- phase 1: pre prefetch + MFMA gates ----
    float pre0[4], pre1r[4], pre2[4], pre3[4];
    if (LAYER==0){
      #pragma unroll
      for (int r=0;r<4;r++){
        int xv = xs[(bq*4+r)*256 + tt];
        const float* pp = P0 + xv*GG + j;
        pre0[r]=pp[0]; pre1r[r]=pp[64]; pre2[r]=pp[128]; pre3[r]=pp[192];
      }
    } else {
      #pragma unroll
      for (int r=0;r<4;r++){
        const unsigned short* pp = pre1 + (size_t)((rb+bq*4+r)*TT + tt)*NN1 + dir*GG + j;
        pre0[r]=bf2f(pp[0]); pre1r[r]=bf2f(pp[64]); pre2[r]=bf2f(pp[128]); pre3[r]=bf2f(pp[192]);
      }
    }
    s8v a0 = *(const s8v*)(hA + l16*72 + q*8);        // k-slice 0 (j 0..31)
    s8v a1 = *(const s8v*)(hA + l16*72 + 32 + q*8);   // k-slice 1 (j 32..63)
    f4v acc0, acc1, acc2, acc3;
    acc0[0]=acc0[1]=acc0[2]=acc0[3]=0.f;
    acc1[0]=acc1[1]=acc1[2]=acc1[3]=0.f;
    acc2[0]=acc2[1]=acc2[2]=acc2[3]=0.f;
    acc3[0]=acc3[1]=acc3[2]=acc3[3]=0.f;
    acc0 = __builtin_amdgcn_mfma_f32_16x16x32_bf16(a0, bf0, acc0, 0,0,0);
    acc0 = __builtin_amdgcn_mfma_f32_16x16x32_bf16(a1, bf1, acc0, 0,0,0);
    acc1 = __builtin_amdgcn_mfma_f32_16x16x32_bf16(a0, bf2, acc1, 0,0,0);
    acc1 = __builtin_amdgcn_mfma_f32_16x16x32_bf16(a1, bf3, acc1, 0,0,0);
    acc2 = __builtin_amdgcn_mfma_f32_16x16x32_bf16(a0, bf4, acc2, 0,0,0);
    acc2 = __builtin_amdgcn_mfma_f32_16x16x32_bf16(a1, bf5, acc2, 0,0,0);
    acc3 = __builtin_amdgcn_mfma_f32_16x16x32_bf16(a0, bf6, acc3, 0,0,0);
    acc3 = __builtin_amdgcn_mfma_f32_16x16x32_bf16(a1, bf7, acc3, 0,0,0);
    {
      int g0 = (w*4+0)*16 + l16;
      *(f4v*)(gfull + g0*20 + q*4) = acc0;
      *(f4v*)(gfull + (g0+16)*20 + q*4) = acc1;
      *(f4v*)(gfull + (g0+32)*20 + q*4) = acc2;
      *(f4v*)(gfull + (g0+48)*20 + q*4) = acc3;
    }
    __syncthreads();   // barrier B: gfull ready
    // ---- phase 2: nonlinearity, thread handles (j, b=bq*4+0..3) ----
    f4v xi = *(const f4v*)(gfull + (      j)*20 + bq*4);
    f4v xf = *(const f4v*)(gfull + ( 64 + j)*20 + bq*4);
    f4v xg = *(const f4v*)(gfull + (128 + j)*20 + bq*4);
    f4v xo = *(const f4v*)(gfull + (192 + j)*20 + bq*4);
    float h0,h1,h2,h3;
    {
      float gi_=xi[0]+pre0[0], gf_=xf[0]+pre1r[0], gg_=xg[0]+pre2[0], go_=xo[0]+pre3[0];
      float cn = sigf(gf_)*c0 + sigf(gi_)*tanhfast(gg_); c0 = cn; h0 = sigf(go_)*tanhfast(cn);
    }
    {
      float gi_=xi[1]+pre0[1], gf_=xf[1]+pre1r[1], gg_=xg[1]+pre2[1], go_=xo[1]+pre3[1];
      float cn = sigf(gf_)*c1 + sigf(gi_)*tanhfast(gg_); c1 = cn; h1 = sigf(go_)*tanhfast(cn);
    }
    {
      float gi_=xi[2]+pre0[2], gf_=xf[2]+pre1r[2], gg_=xg[2]+pre2[2], go_=xo[2]+pre3[2];
      float cn = sigf(gf_)*c2 + sigf(gi_)*tanhfast(gg_); c2 = cn; h2 = sigf(go_)*tanhfast(cn);
    }
    {
      float gi_=xi[3]+pre0[3], gf_=xf[3]+pre1r[3], gg_=xg[3]+pre2[3], go_=xo[3]+pre3[3];
      float cn = sigf(gf_)*c3 + sigf(gi_)*tanhfast(gg_); c3 = cn; h3 = sigf(go_)*tanhfast(cn);
    }
    unsigned short hb0=f2bf(h0), hb1=f2bf(h1), hb2=f2bf(h2), hb3=f2bf(h3);
    hA[(bq*4+0)*72 + j] = hb0;
    hA[(bq*4+1)*72 + j] = hb1;
    hA[(bq*4+2)*72 + j] = hb2;
    hA[(bq*4+3)*72 + j] = hb3;
    hout[(size_t)((rb+bq*4+0)*TT + tt)*DD + dir*HH + j] = hb0;
    hout[(size_t)((rb+bq*4+1)*TT + tt)*DD + dir*HH + j] = hb1;
    hout[(size_t)((rb+bq*4+2)*TT + tt)*DD + dir*HH + j] = hb2;
    hout[(size_t)((rb+bq*4+3)*TT + tt)*DD + dir*HH + j] = hb3;
  }
}

// ---- MFMA GEMM: C[M x N] = A[M x 128](bf16) @ B[N x 128](bf16)^T + bias ----
__global__ __launch_bounds__(256, 2)
void k_gemm_mfma(const unsigned short* __restrict__ A, const unsigned short* __restrict__ Bw,
                 const float* __restrict__ bias, void* __restrict__ C,
                 const int N, const int obf16)
{
  __shared__ __align__(16) unsigned short As[128*136];
  __shared__ __align__(16) unsigned short Bs[64*136];
  const int tid = threadIdx.x;
  const size_t m0 = (size_t)blockIdx.y * 128;
  const int n0 = blockIdx.x * 64;
  #pragma unroll
  for (int i=0;i<8;i++){
    int idx = tid + i*256;
    int r = idx >> 4, c = idx & 15;
    *(ushort8_t*)(As + r*136 + c*8) = *(const ushort8_t*)(A + (m0+r)*128 + c*8);
  }
  #pragma unroll
  for (int i=0;i<4;i++){
    int idx = tid + i*256;
    int r = idx >> 4, c = idx & 15;
    *(ushort8_t*)(Bs + r*136 + c*8) = *(const ushort8_t*)(Bw + (size_t)(n0+r)*128 + c*8);
  }
  __syncthreads();
  const int lane = tid & 63, wid = tid >> 6;
  const int wm = (wid & 1) * 64, wn = (wid >> 1) * 32;
  const int l16 = lane & 15, q = lane >> 4;
  f4v acc[4][2];
  #pragma unroll
  for (int i=0;i<4;i++){
    #pragma unroll
    for (int j=0;j<2;j++){ acc[i][j][0]=0.f; acc[i][j][1]=0.f; acc[i][j][2]=0.f; acc[i][j][3]=0.f; }
  }
  #pragma unroll
  for (int ks=0; ks<4; ks++){
    const int kb = ks*32 + q*8;
    s8v a[4], b[2];
    #pragma unroll
    for (int mt=0;mt<4;mt++) a[mt] = *(const s8v*)(As + (wm + mt*16 + l16)*136 + kb);
    #pragma unroll
    for (int nt=0;nt<2;nt++) b[nt] = *(const s8v*)(Bs + (wn + nt*16 + l16)*136 + kb);
    #pragma unroll
    for (int mt=0;mt<4;mt++){
      #pragma unroll
      for (int nt=0;nt<2;nt++){
        acc[mt][nt] = __builtin_amdgcn_mfma_f32_16x16x32_bf16(a[mt], b[nt], acc[mt][nt], 0, 0, 0);
      }
    }
  }
  #pragma unroll
  for (int mt=0;mt<4;mt++){
    #pragma unroll
    for (int nt=0;nt<2;nt++){
      int col = n0 + wn + nt*16 + l16;
      float bv = bias[col];
      #pragma unroll
      for (int r=0;r<4;r++){
        size_t row = m0 + wm + mt*16 + q*4 + r;
        float v = acc[mt][nt][r] + bv;
        if (obf16) ((unsigned short*)C)[row*N + col] = f2bf(v);
        else       ((float*)C)[row*N + col] = v;
      }
    }
  }
}

// ---------------- gold-path score ----------------
__global__ void k_score(const int* __restrict__ x, const int* __restrict__ tags,
                        const float* __restrict__ em, const float* __restrict__ startv,
                        const float* __restrict__ endv, const float* __restrict__ trans,
                        float* __restrict__ score)
{
  int b = blockIdx.x, lane = threadIdx.x;
  float s = 0.f; int cnt = 0;
  for (int t = lane; t < TT; t += 64){
    int xv = x[b*TT + t];
    int m = (xv != 0);
    cnt += m;
    if (t >= 1 && m){
      int tp = tags[b*TT + t - 1], tc = tags[b*TT + t];
      s += trans[tp*VV + tc] + em[(size_t)(b*TT + t)*VV + tc];
    }
  }
  #pragma unroll
  for (int o=32;o>0;o>>=1){ s += __shfl_down(s,o,64); cnt += __shfl_down(cnt,o,64); }
  if (lane==0){
    int t0 = tags[b*TT];
    s += startv[t0] + em[(size_t)(b*TT)*VV + t0];
    int lt = tags[b*TT + cnt - 1];
    s += endv[lt];
    score[b] = s;
  }
}

// ---------------- CRF partition scan (linear domain) ----------------
__global__ __launch_bounds__(256,2)
void k_crf(const int* __restrict__ x, const float* __restrict__ em,
           const float* __restrict__ etrans, const float* __restrict__ startv,
           const float* __restrict__ eend, float* __restrict__ part)
{
  const int b = blockIdx.x;
  const int j = threadIdx.x & 127;
  const int ih = threadIdx.x >> 7;
  const int wid = threadIdx.x >> 6;
  const int lane = threadIdx.x & 63;
  float et[64];
  #pragma unroll
  for (int u=0;u<64;u++) et[u] = etrans[(ih*64+u)*VV + j];
  __shared__ __align__(16) float abuf[128];
  __shared__ float spbuf[128];
  __shared__ float red[4];
  float L = 0.f, myA = 0.f;
  {
    float e = 0.f;
    if (ih==0){
      e = __expf(startv[j] + em[(size_t)(b*TT)*VV + j]);
      float wsum = e;
      #pragma unroll
      for (int o=32;o>0;o>>=1) wsum += __shfl_down(wsum,o,64);
      if (lane==0) red[wid] = wsum;
    }
    __syncthreads();
    float Z = red[0]+red[1];
    L = logf(Z);
    if (ih==0){ myA = e/Z; abuf[j] = myA; }
    __syncthreads();
  }
  for (int t=1;t<TT;t++){
    if (x[b*TT + t] == 0) break;
    float emv = 0.f;
    if (ih==0) emv = em[(size_t)(b*TT + t)*VV + j];
    float s = 0.f;
    const float4* av = (const float4*)(abuf + ih*64);
    #pragma unroll
    for (int i4=0;i4<16;i4++){
      float4 a = av[i4];
      s = fmaf(a.x, et[4*i4+0], s);
      s = fmaf(a.y, et[4*i4+1], s);
      s = fmaf(a.z, et[4*i4+2], s);
      s = fmaf(a.w, et[4*i4+3], s);
    }
    if (ih==1) spbuf[j] = s;
    __syncthreads();
    float raw = 0.f;
    if (ih==0){
      raw = (s + spbuf[j]) * __expf(emv);
      float wsum = raw;
      #pragma unroll
      for (int o=32;o>0;o>>=1) wsum += __shfl_down(wsum,o,64);
      if (lane==0) red[wid] = wsum;
    }
    __syncthreads();
    float Zt = red[0]+red[1];
    L += logf(Zt);
    if (ih==0){ myA = raw/Zt; abuf[j] = myA; }
    __syncthreads();
  }
  {
    float v = 0.f;
    if (ih==0){
      v = myA * eend[j];
      #pragma unroll
      for (int o=32;o>0;o>>=1) v += __shfl_down(v,o,64);
      if (lane==0) red[wid] = v;
    }
    __syncthreads();
    if (threadIdx.x==0) part[b] = L + logf(red[0]+red[1]);
  }
}

__global__ void k_final(const float* __restrict__ part, const float* __restrict__ score,
                        float* __restrict__ out)
{
  __shared__ float red[8];
  int tid = threadIdx.x;
  float v = part[tid] - score[tid];
  #pragma unroll
  for (int o=32;o>0;o>>=1) v += __shfl_down(v,o,64);
  if ((tid&63)==0) red[tid>>6] = v;
  __syncthreads();
  if (tid==0){
    float s = 0.f;
    #pragma unroll
    for (int i=0;i<8;i++) s += red[i];
    out[0] = s / (float)BB;
  }
}

extern "C" void kernel_launch(void* const* d_in, const int* in_sizes, int n_in,
                              void* d_out, int out_size, void* d_ws, size_t ws_size,
                              hipStream_t stream)
{
  const int*   x        = (const int*)d_in[0];
  const int*   tags     = (const int*)d_in[1];
  const float* emb      = (const float*)d_in[2];
  const float* w_ih_l0  = (const float*)d_in[3];
  const float* w_hh_l0  = (const float*)d_in[4];
  const float* b_ih_l0  = (const float*)d_in[5];
  const float* b_hh_l0  = (const float*)d_in[6];
  const float* w_ih_l0r = (const float*)d_in[7];
  const float* w_hh_l0r = (const float*)d_in[8];
  const float* b_ih_l0r = (const float*)d_in[9];
  const float* b_hh_l0r = (const float*)d_in[10];
  const float* w_ih_l1  = (const float*)d_in[11];
  const float* w_hh_l1  = (const float*)d_in[12];
  const float* b_ih_l1  = (const float*)d_in[13];
  const float* b_hh_l1  = (const float*)d_in[14];
  const float* w_ih_l1r = (const float*)d_in[15];
  const float* w_hh_l1r = (const float*)d_in[16];
  const float* b_ih_l1r = (const float*)d_in[17];
  const float* b_hh_l1r = (const float*)d_in[18];
  const float* lin_w    = (const float*)d_in[19];
  const float* lin_b    = (const float*)d_in[20];
  const float* crf_start= (const float*)d_in[21];
  const float* crf_end  = (const float*)d_in[22];
  const float* crf_trans= (const float*)d_in[23];

  char* ws = (char*)d_ws;
  float*          P0f    = (float*)(ws + 0);                 // 131072
  float*          P0b    = (float*)(ws + 131072);            // 131072
  unsigned short* wB1    = (unsigned short*)(ws + 262144);   // 131072
  unsigned short* linB   = (unsigned short*)(ws + 393216);   // 32768
  float*          bias1  = (float*)(ws + 425984);            // 2048
  float*          etrans = (float*)(ws + 428032);            // 65536
  float*          eend   = (float*)(ws + 493568);            // 512
  float*          scoreA = (float*)(ws + 494080);            // 2048
  float*          partA  = (float*)(ws + 496128);            // 2048
  unsigned short* whhB0f = (unsigned short*)(ws + 498176);   // 32768 each
  unsigned short* whhB0b = (unsigned short*)(ws + 530944);
  unsigned short* whhB1f = (unsigned short*)(ws + 563712);
  unsigned short* whhB1b = (unsigned short*)(ws + 596480);   // end 629248
  const size_t MB1 = 1ull<<20;
  unsigned short* hbuf = (unsigned short*)(ws + MB1);               // 32 MiB bf16
  unsigned short* pre1 = (unsigned short*)(ws + MB1 + 33554432ull); // 128 MiB bf16
  float*          em   = (float*)(ws + MB1 + 33554432ull);          // aliases pre1

  k_prep<<<dim3(405), dim3(256), 0, stream>>>(
      emb, w_ih_l0,b_ih_l0,b_hh_l0, w_ih_l0r,b_ih_l0r,b_hh_l0r,
      w_ih_l1,b_ih_l1,b_hh_l1, w_ih_l1r,b_ih_l1r,b_hh_l1r,
      lin_w, crf_trans, crf_end,
      w_hh_l0, w_hh_l0r, w_hh_l1, w_hh_l1r,
      P0f,P0b,wB1,linB,bias1,etrans,eend,
      whhB0f,whhB0b,whhB1f,whhB1b);

  k_lstm2<0><<<dim3(64), dim3(256), 0, stream>>>(
      x, P0f, P0b, pre1, whhB0f, whhB0b, hbuf);

  k_gemm_mfma<<<dim3(8,1024), dim3(256), 0, stream>>>(
      hbuf, wB1, bias1, (void*)pre1, 512, 1);

  k_lstm2<1><<<dim3(64), dim3(256), 0, stream>>>(
      x, P0f, P0b, pre1, whhB1f, whhB1b, hbuf);

  k_gemm_mfma<<<dim3(2,1024), dim3(256), 0, stream>>>(
      hbuf, linB, lin_b, (void*)em, 128, 0);

  k_score<<<dim3(512), dim3(64), 0, stream>>>(
      x, tags, em, crf_start, crf_end, crf_trans, scoreA);

  k_crf<<<dim3(512), dim3(256), 0, stream>>>(
      x, em, etrans, crf_start, eend, partA);

  k_final<<<dim3(1), dim3(512), 0, stream>>>(partA, scoreA, (float*)d_out);
}